// Round 6
// baseline (817.837 us; speedup 1.0000x reference)
//
#include <hip/hip_runtime.h>
#include <stdint.h>

// SemsegCDRLink R6: 16x16x32 MFMA (acc 48 regs, 4-lane/line gathers),
// W double-buffered in LDS via global_load_lds, ONE barrier per tap,
// zero-row sentinel gathers, frag-order W, fused BN stats.

constexpr int NPT = 200000;   // N voxels
constexpr int KNB = 27;       // kernel taps

typedef unsigned short u16;
typedef __attribute__((ext_vector_type(8))) short     bf16x8;
typedef __attribute__((ext_vector_type(8))) unsigned short u16x8;
typedef __attribute__((ext_vector_type(4))) float     f32x4;

static __device__ __forceinline__ u16 f2bf(float f){
  unsigned int u = __float_as_uint(f);
  unsigned int r = (u + 0x7fffu + ((u >> 16) & 1u)) >> 16;
  return (u16)r;
}
static __device__ __forceinline__ float bf2f(u16 u){
  return __uint_as_float(((unsigned int)u) << 16);
}

// global -> LDS direct copy, 16B per lane; lds dest is wave-uniform base.
static __device__ __forceinline__ void gload_lds16(const void* g, void* l){
  __builtin_amdgcn_global_load_lds(
      (const __attribute__((address_space(1))) void*)g,
      (__attribute__((address_space(3))) void*)(uint32_t)(uintptr_t)l,
      16, 0, 0);
}

// ---------------------------------------------------------------- mask dtype
__global__ void detect_mask_kernel(const int* __restrict__ m32, int* __restrict__ flag){
  if (threadIdx.x == 0 && blockIdx.x == 0){
    int ok = 1;
    for (int i = 0; i < 64; ++i){ int v = m32[i]; if (v != 0 && v != 1) ok = 0; }
    *flag = ok;   // 1 => int32 masks, 0 => uint8 masks
  }
}

// ------------------------------------------------- feat_2d transpose to NHWC
__global__ __launch_bounds__(256) void transpose2d_kernel(const float* __restrict__ in,
                                                          u16* __restrict__ out){
  __shared__ float tile[64][33];
  int bid = blockIdx.x;
  int wt = bid % 5;  int rest = bid / 5;
  int h  = rest % 120; rest /= 120;
  int b  = rest % 4;  int v = rest / 4;
  int w0 = wt * 32;
  int tx = threadIdx.x & 31;
  int ty = threadIdx.x >> 5;
  const float* ip = in + ((size_t)(v*4 + b) * 64) * 19200 + h * 160 + w0;
  #pragma unroll
  for (int cc = 0; cc < 8; ++cc){
    int c = cc * 8 + ty;
    tile[c][tx] = ip[(size_t)c * 19200 + tx];
  }
  __syncthreads();
  u16* op = out + (((size_t)(v*4 + b) * 120 + h) * 160 + w0) * 64;
  int c = threadIdx.x & 63;
  int wg = threadIdx.x >> 6;
  #pragma unroll
  for (int i = 0; i < 8; ++i){
    int w = wg + i * 4;
    op[(size_t)w * 64 + c] = f2bf(tile[c][w]);
  }
}

// ------------------------------------------------------------ weight reshape
// src: [K][cin][cout] f32 -> frag order for 16x16x32:
// dst[((k*NKC+kc)*NCB+cb)*512 + lane*8 + e] =
//   W[k][kc*32+(lane>>4)*8+e][cb*16+(lane&15)]
__global__ void wconvert_kernel(const float* __restrict__ src, u16* __restrict__ dst,
                                int cin, int cout){
  int gid = blockIdx.x * 256 + threadIdx.x;
  int tot = KNB * cin * cout;
  if (gid >= tot) return;
  int ncb = cout / 16;
  int nkc = cin / 32;
  int e    = gid & 7;
  int lane = (gid >> 3) & 63;
  int f    = gid >> 9;
  int cb   = f % ncb;  f /= ncb;
  int kc   = f % nkc;
  int k    = f / nkc;
  int ci = kc * 32 + (lane >> 4) * 8 + e;
  int co = cb * 16 + (lane & 15);
  dst[gid] = f2bf(src[((size_t)k * cin + ci) * cout + co]);
}

// --------------------------------------------------------------- 2D->3D gather
__global__ void stage_a_kernel(const u16* __restrict__ ft, const int* __restrict__ links,
                               const int* __restrict__ cmi, const int* __restrict__ cmo,
                               u16* __restrict__ x0){
  int gid = blockIdx.x * 256 + threadIdx.x;
  if (gid >= NPT * 3) return;
  int i = gid / 3;
  int v = gid - i * 3;
  int outr = cmo[i];
  int l    = cmi[i];
  int b  = links[l*12 + v];
  int h  = links[l*12 + 3 + v];
  int w  = links[l*12 + 6 + v];
  int vl = links[l*12 + 9 + v];
  u16* dst = x0 + (size_t)outr * 192 + v * 64;
  if (vl){
    const u16* src = ft + (((size_t)(v*4 + b) * 120 + h) * 160 + w) * 64;
    #pragma unroll
    for (int j = 0; j < 8; ++j) ((u16x8*)dst)[j] = ((const u16x8*)src)[j];
  } else {
    u16x8 z = {};
    #pragma unroll
    for (int j = 0; j < 8; ++j) ((u16x8*)dst)[j] = z;
  }
}

// --------------------------------- feat3d f32 -> X3 cols [0,96) (stride 192)
__global__ void f3convert_kernel(const float* __restrict__ src, u16* __restrict__ dst){
  long gid = (long)blockIdx.x * 256 + threadIdx.x;
  long tot8 = (long)NPT * 12;           // 96/8 groups per row
  if (gid >= tot8) return;
  int row = (int)(gid / 12);
  int c0  = (int)(gid % 12) * 8;
  const float* s = src + (size_t)row * 96 + c0;
  u16* d = dst + (size_t)row * 192 + c0;
  #pragma unroll
  for (int j = 0; j < 8; ++j) d[j] = f2bf(s[j]);
}

// ------------------------------------------------------------------ conv core
// 256 thr = 4 waves, 128 rows/block (32 rows/wave = 2x 16-row MFMA tiles).
// Sentinel gathers: vidx = mask ? idx : NPT (row NPT is zeroed).
// W double-buffered in LDS: stage W[k+1] issued at TOP of tap k via
// global_load_lds; ONE __syncthreads per tap publishes it (vmcnt drained).
template<int CIN, int COUT, bool F32OUT>
__global__ __launch_bounds__(256)
void conv_kernel(const u16* __restrict__ x0, const u16* __restrict__ wt,
                 const int* __restrict__ in_idx,
                 const uint8_t* __restrict__ mu8, const int* __restrict__ mi32,
                 const int* __restrict__ flagp, void* __restrict__ outp,
                 int outStride, float* __restrict__ st){
  constexpr int NCB    = COUT / 16;
  constexpr int NKC    = CIN / 32;
  constexpr int WELE   = CIN * COUT;          // u16 elems per tap
  constexpr int ROUNDS = (WELE * 2) / 4096;   // 4 waves x 1KB per round
  __shared__ __align__(16) u16 wlds[2 * WELE];
  __shared__ float shS[COUT], shQ[COUT];

  const int tid   = threadIdx.x;
  const int lane  = tid & 63;
  const int wv    = tid >> 6;
  const int r16   = lane & 15;
  const int kgrp  = lane >> 4;
  const int m0    = blockIdx.x * 128;
  const int fInt  = *flagp;

  if (tid < COUT){ shS[tid] = 0.f; shQ[tid] = 0.f; }

  f32x4 acc[2][NCB];
  #pragma unroll
  for (int rt = 0; rt < 2; ++rt)
    #pragma unroll
    for (int cb = 0; cb < NCB; ++cb) acc[rt][cb] = (f32x4)0.0f;

  int rowc[2];
  #pragma unroll
  for (int rt = 0; rt < 2; ++rt){
    int row = m0 + wv * 32 + rt * 16 + r16;
    rowc[rt] = row < NPT ? row : NPT - 1;
  }

  // prologue: stage W[0] -> buf0, load fused vidx[0]
  #pragma unroll
  for (int rd = 0; rd < ROUNDS; ++rd){
    int chunk = rd * 4 + wv;
    gload_lds16((const char*)wt + chunk * 1024 + lane * 16,
                (char*)wlds + chunk * 1024);
  }
  int vC[2];
  #pragma unroll
  for (int rt = 0; rt < 2; ++rt){
    int id = in_idx[rowc[rt]];
    int mv; if (fInt) mv = mi32[rowc[rt]]; else mv = (int)mu8[rowc[rt]];
    vC[rt] = mv ? id : NPT;
  }
  __syncthreads();                           // publishes W[0]

  const u16* xk = x0 + kgrp * 8;             // fold kgrp offset into base

  for (int k = 0; k < KNB; ++k){
    // stage W[k+1] -> other buffer, issued EARLY (hidden under this tap's
    // compute; that buffer's last readers finished at the previous barrier)
    if (k + 1 < KNB){
      const u16* wn = wt + (size_t)(k + 1) * WELE;
      char* wd = (char*)wlds + ((k + 1) & 1) * (WELE * 2);
      #pragma unroll
      for (int rd = 0; rd < ROUNDS; ++rd){
        int chunk = rd * 4 + wv;
        gload_lds16((const char*)wn + chunk * 1024 + lane * 16,
                    wd + chunk * 1024);
      }
    }

    // gather bases for tap k
    const u16* b0 = xk + (size_t)vC[0] * CIN;
    const u16* b1 = xk + (size_t)vC[1] * CIN;

    // prefetch fused vidx[k+1]
    if (k + 1 < KNB){
      #pragma unroll
      for (int rt = 0; rt < 2; ++rt){
        int o = (k + 1) * NPT + rowc[rt];
        int id = in_idx[o];
        int mv; if (fInt) mv = mi32[o]; else mv = (int)mu8[o];
        vC[rt] = mv ? id : NPT;
      }
    }

    // gather A[k]: per instr, 4 lanes share one 64B line (16 rows/instr)
    bf16x8 a0[NKC], a1[NKC];
    #pragma unroll
    for (int kc = 0; kc < NKC; ++kc){
      a0[kc] = *(const bf16x8*)(b0 + kc * 32);
      a1[kc] = *(const bf16x8*)(b1 + kc * 32);
    }

    // MFMAs: B from frag-order LDS buf[k&1] (conflict-free b128)
    const u16* wb = &wlds[(k & 1) * WELE];
    #pragma unroll
    for (int kc = 0; kc < NKC; ++kc){
      #pragma unroll
      for (int cb = 0; cb < NCB; ++cb){
        bf16x8 b = *(const bf16x8*)&wb[((kc * NCB + cb) * 64 + lane) * 8];
        acc[0][cb] = __builtin_amdgcn_mfma_f32_16x16x32_bf16(a0[kc], b, acc[0][cb], 0, 0, 0);
        acc[1][cb] = __builtin_amdgcn_mfma_f32_16x16x32_bf16(a1[kc], b, acc[1][cb], 0, 0, 0);
      }
    }
    __syncthreads();       // end of tap: drains vmcnt -> publishes W[k+1]
  }

  // epilogue: C/D col = lane&15, row = kgrp*4 + j  [m89-verified]
  #pragma unroll
  for (int rt = 0; rt < 2; ++rt){
    #pragma unroll
    for (int cb = 0; cb < NCB; ++cb){
      const int cout = cb * 16 + r16;
      float s = 0.f, q = 0.f;
      #pragma unroll
      for (int j = 0; j < 4; ++j){
        int row = m0 + wv * 32 + rt * 16 + kgrp * 4 + j;
        if (row < NPT){
          float v = acc[rt][cb][j];
          if (F32OUT) ((float*)outp)[(size_t)row * outStride + cout] = v;
          else        ((u16*)outp)[(size_t)row * outStride + cout] = f2bf(v);
          s += v; q += v * v;
        }
      }
      atomicAdd(&shS[cout], s); atomicAdd(&shQ[cout], q);
    }
  }
  __syncthreads();
  if (tid < COUT){
    atomicAdd(&st[tid],        shS[tid]);
    atomicAdd(&st[COUT + tid], shQ[tid]);
  }
}

// --------------------------------------------------------------- BN + ReLU
template<int CCH, bool ISF32>
__global__ void bnrelu_kernel(void* __restrict__ xp, int stride,
                              const float* __restrict__ st,
                              const float* __restrict__ gg, const float* __restrict__ bb){
  const float invN = 1.0f / (float)NPT;
  constexpr int GPR = CCH / 8;
  long tot8 = (long)NPT * GPR;
  for (long e8 = (long)blockIdx.x * 256 + threadIdx.x; e8 < tot8; e8 += (long)gridDim.x * 256){
    int row = (int)(e8 / GPR);
    int c0  = (int)(e8 % GPR) * 8;
    size_t base = (size_t)row * stride + c0;
    #pragma unroll
    for (int j = 0; j < 8; ++j){
      int c = c0 + j;
      float mu  = st[c] * invN;
      float var = st[CCH + c] * invN - mu * mu;
      float rs  = rsqrtf(var + 1e-5f);
      float x;
      if (ISF32) x = ((float*)xp)[base + j];
      else       x = bf2f(((u16*)xp)[base + j]);
      float y = gg[c] * (x - mu) * rs + bb[c];
      y = y > 0.f ? y : 0.f;
      if (ISF32) ((float*)xp)[base + j] = y;
      else       ((u16*)xp)[base + j] = f2bf(y);
    }
  }
}

// =====================================================================
extern "C" void kernel_launch(void* const* d_in, const int* in_sizes, int n_in,
                              void* d_out, int out_size, void* d_ws, size_t ws_size,
                              hipStream_t stream){
  const float* feat2d = (const float*)d_in[0];
  const float* feat3d = (const float*)d_in[1];
  const int*   links  = (const int*)d_in[2];
  const int*   cmi    = (const int*)d_in[3];
  const int*   cmo    = (const int*)d_in[4];
  const int*   inidx  = (const int*)d_in[5];
  const void*  mask   = d_in[6];
  const float* W1 = (const float*)d_in[7];
  const float* g1 = (const float*)d_in[8];
  const float* b1 = (const float*)d_in[9];
  const float* W2 = (const float*)d_in[10];
  const float* g2 = (const float*)d_in[11];
  const float* b2 = (const float*)d_in[12];
  const float* W3 = (const float*)d_in[13];
  const float* g3 = (const float*)d_in[14];
  const float* b3 = (const float*)d_in[15];

  // ws layout (bytes), high-water ~108.3 MB:
  //  [0, 76.80M)           X0 (N+1,192)bf16 ; reused as X3=[F3|H2] (N+1,192)
  //  [76.80M, 106.29M)     FT (29.5M) ; after stage_a reused as Z1 (N+1,64)
  //  [106.29M, 108.28M)    WT1|WT2|WT3 bf16 frag order
  //  [108.28M, ...)        stats (512 f32) + flag
  char* ws = (char*)d_ws;
  u16* X0 = (u16*)(ws + 0);                    // also X3
  constexpr size_t OFF_B  = 76800512;
  u16* FT = (u16*)(ws + OFF_B);
  u16* Z1 = (u16*)(ws + OFF_B);
  u16* WT1 = (u16*)(ws + 106291712);           // 27*192*64 elems
  u16* WT2 = WT1 + 27 * 192 * 64;              // 27*64*96
  u16* WT3 = WT2 + 27 * 64 * 96;               // 27*192*96
  float* ST  = (float*)(ws + 108282368);
  float* ST1 = ST;            // 128 floats (S|Q)
  float* ST2 = ST + 128;      // 192 floats
  float* ST3 = ST + 320;      // 192 floats
  int*   FLAG = (int*)(ST + 512);

  hipMemsetAsync(ST, 0, 513 * sizeof(float), stream);
  detect_mask_kernel<<<1, 64, 0, stream>>>((const int*)mask, FLAG);
  transpose2d_kernel<<<7200, 256, 0, stream>>>(feat2d, FT);
  wconvert_kernel<<<(27*192*64 + 255)/256, 256, 0, stream>>>(W1, WT1, 192, 64);
  wconvert_kernel<<<(27*64*96  + 255)/256, 256, 0, stream>>>(W2, WT2, 64, 96);
  wconvert_kernel<<<(27*192*96 + 255)/256, 256, 0, stream>>>(W3, WT3, 192, 96);
  stage_a_kernel<<<(NPT*3 + 255)/256, 256, 0, stream>>>(FT, links, cmi, cmo, X0);

  // Sentinel rows — AFTER stage_a (FT dead; R4 lesson: zeroing earlier
  // corrupts FT pixels). No kernel writes row NPT, so sentinels persist
  // across graph replays.
  hipMemsetAsync(ws + (size_t)NPT * 384, 0, 384, stream);
  hipMemsetAsync(ws + OFF_B + (size_t)NPT * 128, 0, 128, stream);

  const int nblk = (NPT + 127) / 128;          // 1563
  const uint8_t* m8 = (const uint8_t*)mask;
  const int* m32 = (const int*)mask;

  // layer 1: X0 (N,192) -> Z1 (N,64)          [Z1 overwrites FT]
  conv_kernel<192, 64, false><<<nblk, 256, 0, stream>>>(X0, WT1, inidx, m8, m32, FLAG, Z1, 64, ST1);
  bnrelu_kernel<64, false><<<2048, 256, 0, stream>>>(Z1, 64, ST1, g1, b1);

  // build X3: cols [0,96) = bf16(feat3d)      [overwrites X0 after conv1]
  f3convert_kernel<<<((NPT*12) + 255)/256, 256, 0, stream>>>(feat3d, X0);

  // layer 2: Z1 (N,64) -> X3 cols [96,192)
  conv_kernel<64, 96, false><<<nblk, 256, 0, stream>>>(Z1, WT2, inidx, m8, m32, FLAG, X0 + 96, 192, ST2);
  bnrelu_kernel<96, false><<<2048, 256, 0, stream>>>(X0 + 96, 192, ST2, g2, b2);

  // layer 3: X3 (N,192) -> d_out (N,96) f32
  conv_kernel<192, 96, true><<<nblk, 256, 0, stream>>>(X0, WT3, inidx, m8, m32, FLAG, d_out, 96, ST3);
  bnrelu_kernel<96, true><<<2048, 256, 0, stream>>>(d_out, 96, ST3, g3, b3);
}